// Round 3
// baseline (82.121 us; speedup 1.0000x reference)
//
#include <hip/hip_runtime.h>
#include <stdint.h>

// Problem constants (LSHSoftmax): B=1024, D=512, N=500000, S=32768
#define B_DIM 1024
#define D_DIM 512
#define S_DIM 32768

typedef __attribute__((ext_vector_type(8))) short bf16x8;   // 8 bf16 = 4 VGPRs
typedef __attribute__((ext_vector_type(4))) float f32x4;
typedef __attribute__((ext_vector_type(8))) unsigned short u16x8;

#define AS1 __attribute__((address_space(1)))
#define AS3 __attribute__((address_space(3)))

__device__ __forceinline__ unsigned short f2bf(float f) {
  union { float f; uint32_t u; } x; x.f = f;
  uint32_t r = x.u + 0x7fffu + ((x.u >> 16) & 1u);   // RNE
  return (unsigned short)(r >> 16);
}
__device__ __forceinline__ uint32_t pk2(float a, float b) {
  return (uint32_t)f2bf(a) | ((uint32_t)f2bf(b) << 16);
}

// Convert inputs f32 -> bf16 (A is tiny: 2 MiB -> 1 MiB, reused by all 256 bn-tiles).
__global__ __launch_bounds__(256) void conv_a(const float* __restrict__ A,
                                              unsigned short* __restrict__ Ab) {
  int gid = blockIdx.x * 256 + threadIdx.x;
  const float* src = A + (size_t)gid * 8;
  float4 v0 = *(const float4*)src;
  float4 v1 = *(const float4*)(src + 4);
  u16x8 o;
  o[0] = f2bf(v0.x); o[1] = f2bf(v0.y); o[2] = f2bf(v0.z); o[3] = f2bf(v0.w);
  o[4] = f2bf(v1.x); o[5] = f2bf(v1.y); o[6] = f2bf(v1.z); o[7] = f2bf(v1.w);
  *(u16x8*)(Ab + (size_t)gid * 8) = o;
}

// ---------------------------------------------------------------------------
// Fused gather+GEMM: C[m,n] = sum_k Ab[m,k]*W[ids[n],k] + bias[ids[n]]
// 256x128 tile, BK=64, 8 waves (4r x 2c). A: global_load_lds depth-2 (3 bufs).
// B: reg-staged gather from W (f32) with in-reg bf16 convert + swizzled
// ds_write, depth-1 double-buffer, T14 issue-early/write-late.
// One counted vmcnt(8) per iter. XOR-swizzled LDS reads (conflict-free).
// ---------------------------------------------------------------------------
#define BM 256
#define BN 128
#define BK 64
#define NKT (D_DIM / BK)          // 8 K-tiles
#define A_BYTES (BM * BK * 2)     // 32768
#define B_BYTES (BN * BK * 2)     // 16384
// LDS: A 3 bufs (96 KiB) + B 2 bufs (32 KiB) = 128 KiB -> 1 block/CU, 8 waves.

__global__ __launch_bounds__(512, 1) void gemm_fused(const unsigned short* __restrict__ Ab,
                                                     const float* __restrict__ W,
                                                     const float* __restrict__ bias,
                                                     const int* __restrict__ ids,
                                                     float* __restrict__ out) {
  __shared__ __attribute__((aligned(16))) char lds[3 * A_BYTES + 2 * B_BYTES];
  char* ldsB0 = lds + 3 * A_BYTES;

  const int tid = threadIdx.x;
  const int lane = tid & 63;
  const int w = tid >> 6;          // wave 0..7
  const int wr = w >> 1;           // wave row 0..3 (64 rows each)
  const int wc = w & 1;            // wave col 0..1 (64 cols each)
  const int lq = lane >> 4;        // 0..3
  const int l16 = lane & 15;

  // XCD-aware swizzle: 1024 blocks, 8 XCDs, 128 contiguous tiles per XCD.
  // bm fastest: 4 dispatch-adjacent blocks share the same B panel (L2 hits).
  int id = ((blockIdx.x & 7) << 7) | (blockIdx.x >> 3);
  const int bm = id & 3;           // 4 row tiles
  const int bn = id >> 2;          // 256 col tiles
  const int m0 = bm * BM;
  const int n0 = bn * BN;

  // B-staging role: thread t covers row=t>>2 (0..127), k-seg=t&3 (16 f32 each).
  const int srow = tid >> 2;
  const int sseg = tid & 3;
  const int myid = ids[n0 + srow];                    // gather index (once)
  const float* wbase = W + (size_t)myid * D_DIM + sseg * 16;
  const int sbase = srow * 128 + sseg * 32;           // logical LDS byte
  const int sswz = (srow & 7) << 4;

  f32x4 acc[4][4];
#pragma unroll
  for (int m = 0; m < 4; ++m)
#pragma unroll
    for (int n = 0; n < 4; ++n)
      acc[m][n] = (f32x4)0.0f;

  // ---- A staging: tile kt -> buf kt%3, linear LDS dest, pre-swizzled source.
  auto stageA = [&](int kt) {
    char* ldsA = lds + (kt % 3) * A_BYTES;
#pragma unroll
    for (int j = 0; j < 4; ++j) {               // 32 KB = 8 waves x 4 x 1KB
      const int Pb = j * 8192 + w * 1024;       // wave-uniform dest
      const int P = Pb + lane * 16;
      const int L = P ^ (((P >> 7) & 7) << 4);  // logical byte in tile
      const char* src = (const char*)Ab +
          (size_t)(m0 + (L >> 7)) * (D_DIM * 2) + kt * (BK * 2) + (L & 127);
      __builtin_amdgcn_global_load_lds((const AS1 void*)src,
                                       (AS3 void*)(ldsA + Pb), 16, 0, 0);
    }
  };

  float4 breg[2][4];   // two in-flight B reg sets (indices fold after unroll)

  auto loadB = [&](int kt, int s) {             // issue 4x dwordx4 gather loads
    const float* p = wbase + kt * BK;
    breg[s][0] = *(const float4*)(p + 0);
    breg[s][1] = *(const float4*)(p + 4);
    breg[s][2] = *(const float4*)(p + 8);
    breg[s][3] = *(const float4*)(p + 12);
  };
  auto writeB = [&](int kt, int s) {            // cvt + swizzled ds_write (tile kt)
    char* bb = ldsB0 + (kt & 1) * B_BYTES;
    int4 w0, w1;
    w0.x = pk2(breg[s][0].x, breg[s][0].y); w0.y = pk2(breg[s][0].z, breg[s][0].w);
    w0.z = pk2(breg[s][1].x, breg[s][1].y); w0.w = pk2(breg[s][1].z, breg[s][1].w);
    w1.x = pk2(breg[s][2].x, breg[s][2].y); w1.y = pk2(breg[s][2].z, breg[s][2].w);
    w1.z = pk2(breg[s][3].x, breg[s][3].y); w1.w = pk2(breg[s][3].z, breg[s][3].w);
    *(int4*)(bb + (sbase ^ sswz)) = w0;
    *(int4*)(bb + ((sbase + 16) ^ sswz)) = w1;
  };

  // ---- Prologue ----
  // issue order (oldest->newest): B0(4), A0(4), A1(4)
  loadB(0, 0);
  stageA(0);
  stageA(1);
  asm volatile("s_waitcnt vmcnt(8)" ::: "memory");   // B0 landed
  writeB(0, 0);
  loadB(1, 1);                                       // outstanding: A0,A1,B1
  asm volatile("s_waitcnt vmcnt(8)" ::: "memory");   // A0 landed (allow A1,B1)
  asm volatile("s_waitcnt lgkmcnt(0)" ::: "memory");
  __builtin_amdgcn_s_barrier();

  const int swz = (l16 & 7) << 4;   // fragment-row swizzle (row&7 == l16&7)

#pragma unroll
  for (int kt = 0; kt < NKT; ++kt) {
    __builtin_amdgcn_sched_barrier(0);
    // issue next-next tile (oldest->newest per iter: B(kt+2), A(kt+2))
    if (kt <= NKT - 3) {
      loadB(kt + 2, kt & 1);
      __builtin_amdgcn_sched_barrier(0);
      stageA(kt + 2);
    }
    __builtin_amdgcn_sched_barrier(0);

    // ---- fragment reads from buf kt (published by previous barrier) ----
    const char* ldsA = lds + (kt % 3) * A_BYTES;
    const char* ldsB = ldsB0 + (kt & 1) * B_BYTES;
    bf16x8 af[2][4], bv[2][4];
#pragma unroll
    for (int kk = 0; kk < 2; ++kk) {
#pragma unroll
      for (int m = 0; m < 4; ++m) {
        const int row = wr * 64 + m * 16 + l16;
        const int byte = row * 128 + (kk * 32 + lq * 8) * 2;
        af[kk][m] = *(const bf16x8*)(ldsA + (byte ^ swz));
      }
#pragma unroll
      for (int n = 0; n < 4; ++n) {
        const int row = wc * 64 + n * 16 + l16;
        const int byte = row * 128 + (kk * 32 + lq * 8) * 2;
        bv[kk][n] = *(const bf16x8*)(ldsB + (byte ^ swz));
      }
    }

    __builtin_amdgcn_s_setprio(1);
#pragma unroll
    for (int kk = 0; kk < 2; ++kk)
#pragma unroll
      for (int m = 0; m < 4; ++m)
#pragma unroll
        for (int n = 0; n < 4; ++n)
          acc[m][n] = __builtin_amdgcn_mfma_f32_16x16x32_bf16(af[kk][m], bv[kk][n],
                                                              acc[m][n], 0, 0, 0);
    __builtin_amdgcn_s_setprio(0);
    __builtin_amdgcn_sched_barrier(0);

    if (kt <= NKT - 2) {
      // outstanding (oldest->newest): B(kt+1)(4), A(kt+1)(4), [B(kt+2)(4), A(kt+2)(4)]
      // need B(kt+1) regs (write below) and A(kt+1) LDS (published by barrier).
      if (kt <= NKT - 3)
        asm volatile("s_waitcnt vmcnt(8)" ::: "memory");
      else
        asm volatile("s_waitcnt vmcnt(0)" ::: "memory");
      writeB(kt + 1, (kt & 1) ^ 1);
      __builtin_amdgcn_sched_barrier(0);
      asm volatile("s_waitcnt lgkmcnt(0)" ::: "memory");
      __builtin_amdgcn_s_barrier();
    }
  }

  // ---- Epilogue: C[row][col] = acc + bias[ids[col]] ----
  const int lrow = lq * 4;
#pragma unroll
  for (int n = 0; n < 4; ++n) {
    const int col = n0 + wc * 64 + n * 16 + l16;
    const float bvv = bias[ids[col]];
#pragma unroll
    for (int m = 0; m < 4; ++m) {
      const int rbase = m0 + wr * 64 + m * 16 + lrow;
#pragma unroll
      for (int r = 0; r < 4; ++r) {
        out[(size_t)(rbase + r) * S_DIM + col] = acc[m][n][r] + bvv;
      }
    }
  }
}

extern "C" void kernel_launch(void* const* d_in, const int* in_sizes, int n_in,
                              void* d_out, int out_size, void* d_ws, size_t ws_size,
                              hipStream_t stream) {
  const float* inp  = (const float*)d_in[0];   // [B, D] f32
  const float* W    = (const float*)d_in[1];   // [N, D] f32
  const float* bias = (const float*)d_in[2];   // [N] f32
  const int*   ids  = (const int*)d_in[3];     // [S] int32
  float* out = (float*)d_out;                  // [B, S] f32

  unsigned short* Ab = (unsigned short*)d_ws;  // [B, D] bf16 (1 MiB)

  conv_a<<<(B_DIM * D_DIM / 8) / 256, 256, 0, stream>>>(inp, Ab);

  dim3 grid((B_DIM / BM) * (S_DIM / BN));      // 4 * 256 = 1024 blocks
  gemm_fused<<<grid, 512, 0, stream>>>(Ab, W, bias, ids, out);
}

// Round 4
// 64.933 us; speedup vs baseline: 1.2647x; 1.2647x over previous
//
#include <hip/hip_runtime.h>
#include <stdint.h>

// Problem constants (LSHSoftmax): B=1024, D=512, N=500000, S=32768
#define B_DIM 1024
#define D_DIM 512
#define S_DIM 32768

typedef __attribute__((ext_vector_type(8))) short bf16x8;   // 8 bf16 = 4 VGPRs
typedef __attribute__((ext_vector_type(4))) float f32x4;
typedef __attribute__((ext_vector_type(8))) unsigned short u16x8;

#define AS1 __attribute__((address_space(1)))
#define AS3 __attribute__((address_space(3)))

__device__ __forceinline__ unsigned short f2bf(float f) {
  union { float f; uint32_t u; } x; x.f = f;
  uint32_t r = x.u + 0x7fffu + ((x.u >> 16) & 1u);   // RNE
  return (unsigned short)(r >> 16);
}

// Gather weight rows by sample_ids, convert f32 -> bf16. Also gather bias.
// Bandwidth-bound at full grid parallelism (measured ~20us for ~100MB).
__global__ __launch_bounds__(256) void gather_w(const float* __restrict__ W,
                                                const float* __restrict__ bias,
                                                const int* __restrict__ ids,
                                                unsigned short* __restrict__ Wg,
                                                float* __restrict__ bg) {
  int gid = blockIdx.x * 256 + threadIdx.x;  // 0 .. S*64
  int s = gid >> 6;
  int c = (gid & 63) * 8;
  int sid = ids[s];
  const float* src = W + (size_t)sid * D_DIM + c;
  float4 v0 = *(const float4*)src;
  float4 v1 = *(const float4*)(src + 4);
  u16x8 o;
  o[0] = f2bf(v0.x); o[1] = f2bf(v0.y); o[2] = f2bf(v0.z); o[3] = f2bf(v0.w);
  o[4] = f2bf(v1.x); o[5] = f2bf(v1.y); o[6] = f2bf(v1.z); o[7] = f2bf(v1.w);
  *(u16x8*)(Wg + (size_t)s * D_DIM + c) = o;
  if ((gid & 63) == 0) bg[s] = bias[sid];
}

// Convert inputs f32 -> bf16.
__global__ __launch_bounds__(256) void conv_a(const float* __restrict__ A,
                                              unsigned short* __restrict__ Ab) {
  int gid = blockIdx.x * 256 + threadIdx.x;
  const float* src = A + (size_t)gid * 8;
  float4 v0 = *(const float4*)src;
  float4 v1 = *(const float4*)(src + 4);
  u16x8 o;
  o[0] = f2bf(v0.x); o[1] = f2bf(v0.y); o[2] = f2bf(v0.z); o[3] = f2bf(v0.w);
  o[4] = f2bf(v1.x); o[5] = f2bf(v1.y); o[6] = f2bf(v1.z); o[7] = f2bf(v1.w);
  *(u16x8*)(Ab + (size_t)gid * 8) = o;
}

// ---------------------------------------------------------------------------
// GEMM: C[m,n] = sum_k Ab[m,k]*Wg[n,k] + bg[n]
// 128x128 tile, BK=64, 4 waves (2x2), 2-buffer depth-1 pipeline with counted
// vmcnt + raw barriers, XOR-swizzled LDS (conflict-free ds_read_b128),
// setprio around MFMA, XCD block swizzle. 64 KiB LDS -> 2 blocks/CU so
// epilogue stores / prologue stage of one block overlap compute of the other.
// ---------------------------------------------------------------------------
#define BM 128
#define BN 128
#define BK 64
#define NKT (D_DIM / BK)           // 8 K-tiles
#define A_BYTES (BM * BK * 2)      // 16384
#define B_BYTES (BN * BK * 2)      // 16384
#define BUFBYTES (A_BYTES + B_BYTES) // 32768; 2 buffers = 64 KiB LDS

__global__ __launch_bounds__(256, 2) void gemm_bias(const unsigned short* __restrict__ Ab,
                                                    const unsigned short* __restrict__ Wg,
                                                    const float* __restrict__ bg,
                                                    float* __restrict__ out) {
  __shared__ __attribute__((aligned(16))) char lds[2 * BUFBYTES];

  const int tid = threadIdx.x;
  const int lane = tid & 63;
  const int w = tid >> 6;          // wave 0..3
  const int wr = w >> 1;           // wave row 0..1 (64 rows each)
  const int wc = w & 1;            // wave col 0..1 (64 cols each)
  const int lq = lane >> 4;        // 0..3
  const int l16 = lane & 15;

  // XCD swizzle: 2048 blocks, 8 XCDs, 256 contiguous ids per XCD.
  // bm fastest: 8 dispatch-adjacent blocks on one XCD share the same B panel.
  int id = ((blockIdx.x & 7) << 8) | (blockIdx.x >> 3);
  const int bm = id & 7;           // 8 row tiles
  const int bn = id >> 3;          // 256 col tiles
  const int m0 = bm * BM;
  const int n0 = bn * BN;

  f32x4 acc[4][4];
#pragma unroll
  for (int m = 0; m < 4; ++m)
#pragma unroll
    for (int n = 0; n < 4; ++n)
      acc[m][n] = (f32x4)0.0f;

  // Stage K-tile kt into buffer kt&1. Linear LDS dest (wave-uniform base),
  // inverse-swizzled global source: physical byte P holds logical byte
  // P ^ (((P>>7)&7)<<4) (involution within each 8-row stripe of 128B rows).
  auto stage = [&](int kt) {
    char* ldsA = lds + (kt & 1) * BUFBYTES;
    char* ldsB = ldsA + A_BYTES;
#pragma unroll
    for (int j = 0; j < 4; ++j) {               // A: 16 KB = 4 waves x 4 x 1KB
      const int Pb = j * 4096 + w * 1024;       // wave-uniform
      const int P = Pb + lane * 16;
      const int L = P ^ (((P >> 7) & 7) << 4);  // logical byte in tile
      const char* srcA = (const char*)Ab +
          (size_t)(m0 + (L >> 7)) * (D_DIM * 2) + kt * (BK * 2) + (L & 127);
      __builtin_amdgcn_global_load_lds((const AS1 void*)srcA,
                                       (AS3 void*)(ldsA + Pb), 16, 0, 0);
      const char* srcB = (const char*)Wg +
          (size_t)(n0 + (L >> 7)) * (D_DIM * 2) + kt * (BK * 2) + (L & 127);
      __builtin_amdgcn_global_load_lds((const AS1 void*)srcB,
                                       (AS3 void*)(ldsB + Pb), 16, 0, 0);
    }
  };

  stage(0);                                     // 8 outstanding / wave

  const int swz = (l16 & 7) << 4;   // fragment-row swizzle (row&7 == l16&7)

#pragma unroll
  for (int kt = 0; kt < NKT; ++kt) {
    __builtin_amdgcn_sched_barrier(0);
    if (kt < NKT - 1) {
      stage(kt + 1);                // depth-1 prefetch into buffer (kt+1)&1;
                                    // safe: all reads of that buffer finished
                                    // at the trailing barrier of iter kt-1.
      __builtin_amdgcn_sched_barrier(0);
      asm volatile("s_waitcnt vmcnt(8)" ::: "memory");   // tile kt landed
    } else {
      asm volatile("s_waitcnt vmcnt(0)" ::: "memory");
    }
    __builtin_amdgcn_s_barrier();   // raw barrier: no vmcnt(0) drain
    __builtin_amdgcn_sched_barrier(0);

    const char* ldsA = lds + (kt & 1) * BUFBYTES;
    const char* ldsB = ldsA + A_BYTES;

    bf16x8 af[2][4], bv[2][4];
#pragma unroll
    for (int kk = 0; kk < 2; ++kk) {
#pragma unroll
      for (int m = 0; m < 4; ++m) {
        const int row = wr * 64 + m * 16 + l16;
        const int byte = row * 128 + (kk * 32 + lq * 8) * 2;
        af[kk][m] = *(const bf16x8*)(ldsA + (byte ^ swz));
      }
#pragma unroll
      for (int n = 0; n < 4; ++n) {
        const int row = wc * 64 + n * 16 + l16;
        const int byte = row * 128 + (kk * 32 + lq * 8) * 2;
        bv[kk][n] = *(const bf16x8*)(ldsB + (byte ^ swz));
      }
    }

    __builtin_amdgcn_s_setprio(1);
#pragma unroll
    for (int kk = 0; kk < 2; ++kk)
#pragma unroll
      for (int m = 0; m < 4; ++m)
#pragma unroll
        for (int n = 0; n < 4; ++n)
          acc[m][n] = __builtin_amdgcn_mfma_f32_16x16x32_bf16(af[kk][m], bv[kk][n],
                                                              acc[m][n], 0, 0, 0);
    __builtin_amdgcn_s_setprio(0);

    __builtin_amdgcn_sched_barrier(0);
    __builtin_amdgcn_s_barrier();   // all waves done reading buf kt&1 before
                                    // stage(kt+2) (next iter) overwrites it
  }

  // Epilogue: C layout col = l16, row = lq*4 + r (m89-verified). Fuse bias.
  const int lrow = lq * 4;
#pragma unroll
  for (int n = 0; n < 4; ++n) {
    const int col = n0 + wc * 64 + n * 16 + l16;
    const float bvv = bg[col];
#pragma unroll
    for (int m = 0; m < 4; ++m) {
      const int rbase = m0 + wr * 64 + m * 16 + lrow;
#pragma unroll
      for (int r = 0; r < 4; ++r) {
        out[(size_t)(rbase + r) * S_DIM + col] = acc[m][n][r] + bvv;
      }
    }
  }
}

extern "C" void kernel_launch(void* const* d_in, const int* in_sizes, int n_in,
                              void* d_out, int out_size, void* d_ws, size_t ws_size,
                              hipStream_t stream) {
  const float* inp  = (const float*)d_in[0];   // [B, D] f32
  const float* W    = (const float*)d_in[1];   // [N, D] f32
  const float* bias = (const float*)d_in[2];   // [N] f32
  const int*   ids  = (const int*)d_in[3];     // [S] int32
  float* out = (float*)d_out;                  // [B, S] f32

  unsigned short* Wg = (unsigned short*)d_ws;                       // [S,D] bf16 (32 MiB)
  unsigned short* Ab = (unsigned short*)((char*)d_ws +
                        (size_t)S_DIM * D_DIM * 2);                 // [B,D] bf16 (1 MiB)
  float* bg = (float*)((char*)d_ws +
                        (size_t)S_DIM * D_DIM * 2 + (size_t)B_DIM * D_DIM * 2); // [S] f32

  gather_w<<<S_DIM / 4, 256, 0, stream>>>(W, bias, ids, Wg, bg);
  conv_a<<<(B_DIM * D_DIM / 8) / 256, 256, 0, stream>>>(inp, Ab);

  dim3 grid((B_DIM / BM) * (S_DIM / BN));   // 8 * 256 = 2048 blocks
  gemm_bias<<<grid, 256, 0, stream>>>(Ab, Wg, bg, out);
}

// Round 5
// 64.091 us; speedup vs baseline: 1.2813x; 1.0131x over previous
//
#include <hip/hip_runtime.h>
#include <stdint.h>

// Problem constants (LSHSoftmax): B=1024, D=512, N=500000, S=32768
#define B_DIM 1024
#define D_DIM 512
#define S_DIM 32768

typedef __attribute__((ext_vector_type(8))) short bf16x8;   // 8 bf16 = 4 VGPRs
typedef __attribute__((ext_vector_type(4))) float f32x4;
typedef __attribute__((ext_vector_type(8))) unsigned short u16x8;

#define AS1 __attribute__((address_space(1)))
#define AS3 __attribute__((address_space(3)))

__device__ __forceinline__ unsigned short f2bf(float f) {
  union { float f; uint32_t u; } x; x.f = f;
  uint32_t r = x.u + 0x7fffu + ((x.u >> 16) & 1u);   // RNE
  return (unsigned short)(r >> 16);
}

// Fused prep: blocks [0, 8192) gather+convert W rows by ids (4 rows/block)
// and gather bias; blocks [8192, 8448) convert inputs A f32->bf16.
#define GATHER_BLOCKS (S_DIM / 4)              // 8192
#define CONV_BLOCKS (B_DIM * D_DIM / 8 / 256)  // 256

__global__ __launch_bounds__(256) void prep(const float* __restrict__ W,
                                            const float* __restrict__ bias,
                                            const int* __restrict__ ids,
                                            const float* __restrict__ A,
                                            unsigned short* __restrict__ Wg,
                                            unsigned short* __restrict__ Ab,
                                            float* __restrict__ bg) {
  if (blockIdx.x < GATHER_BLOCKS) {
    int gid = blockIdx.x * 256 + threadIdx.x;  // 0 .. S*64
    int s = gid >> 6;
    int c = (gid & 63) * 8;
    int sid = ids[s];
    const float* src = W + (size_t)sid * D_DIM + c;
    float4 v0 = *(const float4*)src;
    float4 v1 = *(const float4*)(src + 4);
    u16x8 o;
    o[0] = f2bf(v0.x); o[1] = f2bf(v0.y); o[2] = f2bf(v0.z); o[3] = f2bf(v0.w);
    o[4] = f2bf(v1.x); o[5] = f2bf(v1.y); o[6] = f2bf(v1.z); o[7] = f2bf(v1.w);
    *(u16x8*)(Wg + (size_t)s * D_DIM + c) = o;
    if ((gid & 63) == 0) bg[s] = bias[sid];
  } else {
    int gid = (blockIdx.x - GATHER_BLOCKS) * 256 + threadIdx.x;
    const float* src = A + (size_t)gid * 8;
    float4 v0 = *(const float4*)src;
    float4 v1 = *(const float4*)(src + 4);
    u16x8 o;
    o[0] = f2bf(v0.x); o[1] = f2bf(v0.y); o[2] = f2bf(v0.z); o[3] = f2bf(v0.w);
    o[4] = f2bf(v1.x); o[5] = f2bf(v1.y); o[6] = f2bf(v1.z); o[7] = f2bf(v1.w);
    *(u16x8*)(Ab + (size_t)gid * 8) = o;
  }
}

// ---------------------------------------------------------------------------
// GEMM: C[m,n] = sum_k Ab[m,k]*Wg[n,k] + bg[n]
// 128x128 tile, BK=64, 8 waves (2r x 4c, 64x32 output each), 2-buffer depth-1
// pipeline with counted vmcnt(4) + raw barriers, XOR-swizzled LDS
// (conflict-free ds_read_b128), setprio around MFMA, XCD block swizzle.
// 64 KiB LDS + <=128 VGPR -> 2 blocks/CU = 16 waves/CU (4/SIMD) so pipeline
// stalls of one block hide under the other's MFMA.
// ---------------------------------------------------------------------------
#define BM 128
#define BN 128
#define BK 64
#define NKT (D_DIM / BK)           // 8 K-tiles
#define A_BYTES (BM * BK * 2)      // 16384
#define B_BYTES (BN * BK * 2)      // 16384
#define BUFBYTES (A_BYTES + B_BYTES) // 32768; 2 buffers = 64 KiB LDS

__global__ __launch_bounds__(512, 4) void gemm_bias(const unsigned short* __restrict__ Ab,
                                                    const unsigned short* __restrict__ Wg,
                                                    const float* __restrict__ bg,
                                                    float* __restrict__ out) {
  __shared__ __attribute__((aligned(16))) char lds[2 * BUFBYTES];

  const int tid = threadIdx.x;
  const int lane = tid & 63;
  const int w = tid >> 6;          // wave 0..7
  const int wr = w >> 2;           // wave row 0..1 (64 rows each)
  const int wc = w & 3;            // wave col 0..3 (32 cols each)
  const int lq = lane >> 4;        // 0..3
  const int l16 = lane & 15;

  // XCD swizzle: 2048 blocks, 8 XCDs, 256 contiguous ids per XCD.
  // bm fastest: 8 dispatch-adjacent blocks on one XCD share the same B panel;
  // per XCD: 32 B panels (4 MiB bf16, L2-fit) x 8 bm reuse.
  int id = ((blockIdx.x & 7) << 8) | (blockIdx.x >> 3);
  const int bm = id & 7;           // 8 row tiles
  const int bn = id >> 3;          // 256 col tiles
  const int m0 = bm * BM;
  const int n0 = bn * BN;

  f32x4 acc[4][2];
#pragma unroll
  for (int m = 0; m < 4; ++m)
#pragma unroll
    for (int n = 0; n < 2; ++n)
      acc[m][n] = (f32x4)0.0f;

  // Stage K-tile kt into buffer kt&1. Linear LDS dest (wave-uniform base),
  // inverse-swizzled global source: physical byte P holds logical byte
  // P ^ (((P>>7)&7)<<4) (involution within each 8-row stripe of 128B rows).
  // 32 KB total / (512 lanes x 16B) = 4 issues/thread: 2 A + 2 B.
  auto stage = [&](int kt) {
    char* ldsA = lds + (kt & 1) * BUFBYTES;
    char* ldsB = ldsA + A_BYTES;
#pragma unroll
    for (int j = 0; j < 2; ++j) {               // A: 16 KB = 8 waves x 2 x 1KB
      const int Pb = j * 8192 + w * 1024;       // wave-uniform
      const int P = Pb + lane * 16;
      const int L = P ^ (((P >> 7) & 7) << 4);  // logical byte in tile
      const char* srcA = (const char*)Ab +
          (size_t)(m0 + (L >> 7)) * (D_DIM * 2) + kt * (BK * 2) + (L & 127);
      __builtin_amdgcn_global_load_lds((const AS1 void*)srcA,
                                       (AS3 void*)(ldsA + Pb), 16, 0, 0);
      const char* srcB = (const char*)Wg +
          (size_t)(n0 + (L >> 7)) * (D_DIM * 2) + kt * (BK * 2) + (L & 127);
      __builtin_amdgcn_global_load_lds((const AS1 void*)srcB,
                                       (AS3 void*)(ldsB + Pb), 16, 0, 0);
    }
  };

  stage(0);                                     // 4 outstanding / wave

  const int swz = (l16 & 7) << 4;   // fragment-row swizzle (row&7 == l16&7)

#pragma unroll
  for (int kt = 0; kt < NKT; ++kt) {
    __builtin_amdgcn_sched_barrier(0);
    if (kt < NKT - 1) {
      stage(kt + 1);                // depth-1 prefetch into buffer (kt+1)&1;
                                    // safe: all reads of that buffer finished
                                    // at the trailing barrier of iter kt-1.
      __builtin_amdgcn_sched_barrier(0);
      asm volatile("s_waitcnt vmcnt(4)" ::: "memory");   // tile kt landed
    } else {
      asm volatile("s_waitcnt vmcnt(0)" ::: "memory");
    }
    __builtin_amdgcn_s_barrier();   // raw barrier: no vmcnt(0) drain
    __builtin_amdgcn_sched_barrier(0);

    const char* ldsA = lds + (kt & 1) * BUFBYTES;
    const char* ldsB = ldsA + A_BYTES;

    // Per-kk fragment loads (halves register pressure vs all-upfront).
#pragma unroll
    for (int kk = 0; kk < 2; ++kk) {
      bf16x8 af[4], bv[2];
#pragma unroll
      for (int m = 0; m < 4; ++m) {
        const int row = wr * 64 + m * 16 + l16;
        const int byte = row * 128 + (kk * 32 + lq * 8) * 2;
        af[m] = *(const bf16x8*)(ldsA + (byte ^ swz));
      }
#pragma unroll
      for (int n = 0; n < 2; ++n) {
        const int row = wc * 32 + n * 16 + l16;
        const int byte = row * 128 + (kk * 32 + lq * 8) * 2;
        bv[n] = *(const bf16x8*)(ldsB + (byte ^ swz));
      }
      __builtin_amdgcn_s_setprio(1);
#pragma unroll
      for (int m = 0; m < 4; ++m)
#pragma unroll
        for (int n = 0; n < 2; ++n)
          acc[m][n] = __builtin_amdgcn_mfma_f32_16x16x32_bf16(af[m], bv[n],
                                                              acc[m][n], 0, 0, 0);
      __builtin_amdgcn_s_setprio(0);
    }

    __builtin_amdgcn_sched_barrier(0);
    __builtin_amdgcn_s_barrier();   // all waves done reading buf kt&1 before
                                    // stage(kt+2) (next iter) overwrites it
  }

  // Epilogue: C layout col = l16, row = lq*4 + r (m89-verified). Fuse bias.
  const int lrow = lq * 4;
#pragma unroll
  for (int n = 0; n < 2; ++n) {
    const int col = n0 + wc * 32 + n * 16 + l16;
    const float bvv = bg[col];
#pragma unroll
    for (int m = 0; m < 4; ++m) {
      const int rbase = m0 + wr * 64 + m * 16 + lrow;
#pragma unroll
      for (int r = 0; r < 4; ++r) {
        out[(size_t)(rbase + r) * S_DIM + col] = acc[m][n][r] + bvv;
      }
    }
  }
}

extern "C" void kernel_launch(void* const* d_in, const int* in_sizes, int n_in,
                              void* d_out, int out_size, void* d_ws, size_t ws_size,
                              hipStream_t stream) {
  const float* inp  = (const float*)d_in[0];   // [B, D] f32
  const float* W    = (const float*)d_in[1];   // [N, D] f32
  const float* bias = (const float*)d_in[2];   // [N] f32
  const int*   ids  = (const int*)d_in[3];     // [S] int32
  float* out = (float*)d_out;                  // [B, S] f32

  unsigned short* Wg = (unsigned short*)d_ws;                       // [S,D] bf16 (32 MiB)
  unsigned short* Ab = (unsigned short*)((char*)d_ws +
                        (size_t)S_DIM * D_DIM * 2);                 // [B,D] bf16 (1 MiB)
  float* bg = (float*)((char*)d_ws +
                        (size_t)S_DIM * D_DIM * 2 + (size_t)B_DIM * D_DIM * 2); // [S] f32

  prep<<<GATHER_BLOCKS + CONV_BLOCKS, 256, 0, stream>>>(W, bias, ids, inp, Wg, Ab, bg);

  dim3 grid((B_DIM / BM) * (S_DIM / BN));   // 8 * 256 = 2048 blocks
  gemm_bias<<<grid, 512, 0, stream>>>(Ab, Wg, bg, out);
}